// Round 2
// baseline (4939.738 us; speedup 1.0000x reference)
//
#include <hip/hip_runtime.h>
#include <hip/hip_bf16.h>

#define BATCH 256
#define LAT 128
#define H 256
#define OUTD 64
#define SEQ 512

typedef short bf16x8 __attribute__((ext_vector_type(8)));
typedef float f32x4  __attribute__((ext_vector_type(4)));

__device__ __forceinline__ float sigm(float x)  { return 1.f / (1.f + __expf(-x)); }
__device__ __forceinline__ float tanhf_(float x){ return 1.f - 2.f / (__expf(2.f * x) + 1.f); }

// ---------------- Prologue 0: convert recurrent/output weights f32 -> bf16 ----------------
__global__ void lstm_convert_weights(const float* __restrict__ Whh0,
                                     const float* __restrict__ Wih1,
                                     const float* __restrict__ Whh1,
                                     const float* __restrict__ Wout,
                                     __hip_bfloat16* __restrict__ Whh0b,
                                     __hip_bfloat16* __restrict__ Wih1b,
                                     __hip_bfloat16* __restrict__ Whh1b,
                                     __hip_bfloat16* __restrict__ Woutb)
{
    int t = blockIdx.x * 256 + threadIdx.x;
    if (t < 262144)       Whh0b[t]            = __float2bfloat16(Whh0[t]);
    else if (t < 524288)  Wih1b[t - 262144]   = __float2bfloat16(Wih1[t - 262144]);
    else if (t < 786432)  Whh1b[t - 524288]   = __float2bfloat16(Whh1[t - 524288]);
    else if (t < 802816)  Woutb[t - 786432]   = __float2bfloat16(Wout[t - 786432]);
}

// ---------------- Prologue 1: init h/c for both layers, x0, layer-1 bias vec ----------------
__global__ void lstm_prologue_init(const float* __restrict__ z,
                                   const float* __restrict__ Whid,
                                   const float* __restrict__ bhid,
                                   const float* __restrict__ Wcell,
                                   const float* __restrict__ bcell,
                                   const float* __restrict__ Win,
                                   const float* __restrict__ bin,
                                   const float* __restrict__ bih1,
                                   const float* __restrict__ bhh1,
                                   __hip_bfloat16* __restrict__ h0init,
                                   __hip_bfloat16* __restrict__ h1init,
                                   float* __restrict__ c0,
                                   float* __restrict__ c1,
                                   float* __restrict__ x0,
                                   float* __restrict__ gxb1)
{
    int t = blockIdx.x * 256 + threadIdx.x;
    if (t < 131072) {                    // hidden init: [256 x 512]
        int b = t >> 9, col = t & 511;
        const float* w  = Whid + col * LAT;
        const float* zr = z + b * LAT;
        float acc = bhid[col];
        for (int k = 0; k < LAT; k++) acc += zr[k] * w[k];
        if (col < H) h0init[b * H + col] = __float2bfloat16(acc);
        else         h1init[b * H + (col - H)] = __float2bfloat16(acc);
    } else if (t < 262144) {             // cell init: [256 x 512]
        int tt = t - 131072;
        int b = tt >> 9, col = tt & 511;
        const float* w  = Wcell + col * LAT;
        const float* zr = z + b * LAT;
        float acc = bcell[col];
        for (int k = 0; k < LAT; k++) acc += zr[k] * w[k];
        if (col < H) c0[b * H + col] = acc;
        else         c1[b * H + (col - H)] = acc;
    } else if (t < 327680) {             // x0 = z @ fc_input_w.T + b : [256 x 256]
        int tt = t - 262144;
        int b = tt >> 8, j = tt & 255;
        const float* w  = Win + j * LAT;
        const float* zr = z + b * LAT;
        float acc = bin[j];
        for (int k = 0; k < LAT; k++) acc += zr[k] * w[k];
        x0[b * H + j] = acc;
    } else if (t < 328704) {             // layer-1 gate bias vector [1024]
        int g = t - 327680;
        gxb1[g] = bih1[g] + bhh1[g];
    }
}

// ---------------- Prologue 2: gx0 = x0 @ W_ih0.T + b_ih0 + b_hh0  [256 x 1024] ----------------
__global__ void lstm_prologue_gx0(const float* __restrict__ x0,
                                  const float* __restrict__ Wih0,
                                  const float* __restrict__ bih0,
                                  const float* __restrict__ bhh0,
                                  float* __restrict__ gxb0)
{
    __shared__ float xs[H];
    int b = blockIdx.y;
    int n = blockIdx.x * 256 + threadIdx.x;
    xs[threadIdx.x] = x0[b * H + threadIdx.x];
    __syncthreads();
    const float* w = Wih0 + n * H;
    float acc = bih0[n] + bhh0[n];
    for (int k = 0; k < H; k++) acc += xs[k] * w[k];
    gxb0[b * 4 * H + n] = acc;
}

// ---------------- Per-step kernel (layer-skewed pipeline) ----------------
// blocks [0,256):   layer0 step k       (active k in [0,512))
// blocks [256,512): layer1 step k-1     (active k in [1,513))
// blocks [512,528): out-proj step k-2   (active k in [2,514))
__global__ __launch_bounds__(256)
void lstm_step_kernel(int k,
                      const __hip_bfloat16* __restrict__ h0_prev, __hip_bfloat16* __restrict__ h0_cur,
                      const __hip_bfloat16* __restrict__ h1_prev, __hip_bfloat16* __restrict__ h1_cur,
                      float* __restrict__ c0, float* __restrict__ c1,
                      const float* __restrict__ gxb0, const float* __restrict__ gxb1,
                      const __hip_bfloat16* __restrict__ Whh0,
                      const __hip_bfloat16* __restrict__ Wih1,
                      const __hip_bfloat16* __restrict__ Whh1,
                      const __hip_bfloat16* __restrict__ Wout,
                      const float* __restrict__ bout,
                      float* __restrict__ out)
{
    const int w    = blockIdx.x;
    const int tid  = threadIdx.x;
    const int wave = tid >> 6;          // 0..3 : gate index (i,f,g,o) or out-col tile
    const int lane = tid & 63;
    const int q    = lane >> 4;         // quad
    const int ln   = lane & 15;         // m (A rows) / n (B rows) / C col

    __shared__ float sm[4][16][17];     // +1 pad breaks 4-way bank conflict

    if (w < 256) {                      // ---- layer 0, step k ----
        if (k >= SEQ) return;
        const int bg = w >> 4, cg = w & 15;
        f32x4 acc = {0.f, 0.f, 0.f, 0.f};
        const __hip_bfloat16* arow = h0_prev + (bg * 16 + ln) * H;
        const __hip_bfloat16* brow = Whh0 + (wave * H + cg * 16 + ln) * H;
        for (int kk = 0; kk < 8; kk++) {
            bf16x8 a  = *(const bf16x8*)(arow + kk * 32 + q * 8);
            bf16x8 bb = *(const bf16x8*)(brow + kk * 32 + q * 8);
            acc = __builtin_amdgcn_mfma_f32_16x16x32_bf16(a, bb, acc, 0, 0, 0);
        }
        for (int r = 0; r < 4; r++) {
            int m = q * 4 + r;
            int b = bg * 16 + m;
            sm[wave][m][ln] = acc[r] + gxb0[b * 1024 + wave * H + cg * 16 + ln];
        }
        __syncthreads();
        const int m = tid >> 4, n = tid & 15;
        const int b = bg * 16 + m, j = cg * 16 + n;
        float xi = sm[0][m][n], xf = sm[1][m][n], xg = sm[2][m][n], xo = sm[3][m][n];
        float c = sigm(xf) * c0[b * H + j] + sigm(xi) * tanhf_(xg);
        c0[b * H + j] = c;
        h0_cur[b * H + j] = __float2bfloat16(sigm(xo) * tanhf_(c));
    } else if (w < 512) {               // ---- layer 1, step k-1 ----
        if (k < 1 || k > SEQ) return;
        const int ww = w - 256;
        const int bg = ww >> 4, cg = ww & 15;
        f32x4 acc = {0.f, 0.f, 0.f, 0.f};
        const __hip_bfloat16* arow0 = h0_prev + (bg * 16 + ln) * H;      // x input = h0_{k-1}
        const __hip_bfloat16* brow0 = Wih1 + (wave * H + cg * 16 + ln) * H;
        for (int kk = 0; kk < 8; kk++) {
            bf16x8 a  = *(const bf16x8*)(arow0 + kk * 32 + q * 8);
            bf16x8 bb = *(const bf16x8*)(brow0 + kk * 32 + q * 8);
            acc = __builtin_amdgcn_mfma_f32_16x16x32_bf16(a, bb, acc, 0, 0, 0);
        }
        const __hip_bfloat16* arow1 = h1_prev + (bg * 16 + ln) * H;      // state h1_{k-2}
        const __hip_bfloat16* brow1 = Whh1 + (wave * H + cg * 16 + ln) * H;
        for (int kk = 0; kk < 8; kk++) {
            bf16x8 a  = *(const bf16x8*)(arow1 + kk * 32 + q * 8);
            bf16x8 bb = *(const bf16x8*)(brow1 + kk * 32 + q * 8);
            acc = __builtin_amdgcn_mfma_f32_16x16x32_bf16(a, bb, acc, 0, 0, 0);
        }
        for (int r = 0; r < 4; r++) {
            int m = q * 4 + r;
            sm[wave][m][ln] = acc[r] + gxb1[wave * H + cg * 16 + ln];
        }
        __syncthreads();
        const int m = tid >> 4, n = tid & 15;
        const int b = bg * 16 + m, j = cg * 16 + n;
        float xi = sm[0][m][n], xf = sm[1][m][n], xg = sm[2][m][n], xo = sm[3][m][n];
        float c = sigm(xf) * c1[b * H + j] + sigm(xi) * tanhf_(xg);
        c1[b * H + j] = c;
        h1_cur[b * H + j] = __float2bfloat16(sigm(xo) * tanhf_(c));
    } else {                            // ---- output projection, step k-2 ----
        if (k < 2) return;
        const int t  = k - 2;
        const int bg = w - 512;
        f32x4 acc = {0.f, 0.f, 0.f, 0.f};
        const __hip_bfloat16* arow = h1_prev + (bg * 16 + ln) * H;       // h1_{k-2}
        const __hip_bfloat16* brow = Wout + (wave * 16 + ln) * H;
        for (int kk = 0; kk < 8; kk++) {
            bf16x8 a  = *(const bf16x8*)(arow + kk * 32 + q * 8);
            bf16x8 bb = *(const bf16x8*)(brow + kk * 32 + q * 8);
            acc = __builtin_amdgcn_mfma_f32_16x16x32_bf16(a, bb, acc, 0, 0, 0);
        }
        const float bo = bout[wave * 16 + ln];
        for (int r = 0; r < 4; r++) {
            int m = q * 4 + r;
            int b = bg * 16 + m;
            out[b * (SEQ * OUTD) + t * OUTD + wave * 16 + ln] = acc[r] + bo;
        }
    }
}

extern "C" void kernel_launch(void* const* d_in, const int* in_sizes, int n_in,
                              void* d_out, int out_size, void* d_ws, size_t ws_size,
                              hipStream_t stream) {
    const float* z     = (const float*)d_in[0];
    const float* Whid  = (const float*)d_in[1];
    const float* bhid  = (const float*)d_in[2];
    const float* Wcell = (const float*)d_in[3];
    const float* bcell = (const float*)d_in[4];
    const float* Win   = (const float*)d_in[5];
    const float* bin   = (const float*)d_in[6];
    const float* Wih0  = (const float*)d_in[7];
    const float* Whh0  = (const float*)d_in[8];
    const float* bih0  = (const float*)d_in[9];
    const float* bhh0  = (const float*)d_in[10];
    const float* Wih1  = (const float*)d_in[11];
    const float* Whh1  = (const float*)d_in[12];
    const float* bih1  = (const float*)d_in[13];
    const float* bhh1  = (const float*)d_in[14];
    const float* Wout  = (const float*)d_in[15];
    const float* bout  = (const float*)d_in[16];
    float* out = (float*)d_out;

    // workspace carve-up (~4 MB), all 16B-aligned
    float* gxb0 = (float*)d_ws;                  // [256][1024]
    float* gxb1 = gxb0 + 262144;                 // [1024]
    float* c0   = gxb1 + 1024;                   // [256][256]
    float* c1   = c0 + 65536;                    // [256][256]
    float* x0   = c1 + 65536;                    // [256][256]
    __hip_bfloat16* h0b0 = (__hip_bfloat16*)(x0 + 65536);   // [256][256] bf16
    __hip_bfloat16* h0b1 = h0b0 + 65536;
    __hip_bfloat16* h1b0 = h0b1 + 65536;
    __hip_bfloat16* h1b1 = h1b0 + 65536;
    __hip_bfloat16* Whh0b = h1b1 + 65536;        // [1024][256] bf16
    __hip_bfloat16* Wih1b = Whh0b + 262144;
    __hip_bfloat16* Whh1b = Wih1b + 262144;
    __hip_bfloat16* Woutb = Whh1b + 262144;      // [64][256]

    lstm_convert_weights<<<3136, 256, 0, stream>>>(Whh0, Wih1, Whh1, Wout,
                                                   Whh0b, Wih1b, Whh1b, Woutb);
    lstm_prologue_init<<<1284, 256, 0, stream>>>(z, Whid, bhid, Wcell, bcell, Win, bin,
                                                 bih1, bhh1, h0b1, h1b1, c0, c1, x0, gxb1);
    lstm_prologue_gx0<<<dim3(4, 256), 256, 0, stream>>>(x0, Wih0, bih0, bhh0, gxb0);

    for (int k = 0; k <= SEQ + 1; k++) {
        __hip_bfloat16* h0p = (k & 1) ? h0b0 : h0b1;   // h0_{k-1}
        __hip_bfloat16* h0c = (k & 1) ? h0b1 : h0b0;   // h0_k
        __hip_bfloat16* h1p = (k & 1) ? h1b1 : h1b0;   // h1_{k-2}
        __hip_bfloat16* h1c = (k & 1) ? h1b0 : h1b1;   // h1_{k-1}
        lstm_step_kernel<<<528, 256, 0, stream>>>(k, h0p, h0c, h1p, h1c, c0, c1,
                                                  gxb0, gxb1, Whh0b, Wih1b, Whh1b, Woutb, bout, out);
    }
}